// Round 11
// baseline (308.057 us; speedup 1.0000x reference)
//
#include <hip/hip_runtime.h>

typedef float v4f __attribute__((ext_vector_type(4)));

#define NB 8        // batch
#define NL 24       // layers
#define NR 64       // chunks
#define ND 4096     // DL
#define NFUSED 1536
#define NTF 1024
#define NPF 512
#define KP 4096     // DP
#define FKC 12      // F k-chunks of 128
#define GRID 1024   // all blocks co-resident (launch_bounds(256,4) => >=4 blk/CU)

// workspace float offsets
#define WS_CNT   0          // 2 counters (uint), padded
#define WS_FACC  64         // 4*8*1536 = 49152  -> 49216
#define WS_GATE  49216      // 192               -> 49408
#define WS_PLA   49408      // 196608            -> 246016
#define WS_PLB   246016     // 196608            -> 442624
#define WS_CA    442624     // 262144            -> 704768
#define WS_CBT   704768     // 262144            -> 966912
#define WS_PFA   966912     // 393216            -> 1360128
#define WS_PFB   1360128    // 393216            -> 1753344
#define WS_ZERO_N 49216     // counters + fAcc

__device__ __forceinline__ void nt(float v, float* p) {
  __builtin_nontemporal_store(v, p);
}

// Single fused kernel: 3 phases separated by flag barriers.
// All inter-phase ws stores are nontemporal (coherent at MALL);
// fAcc is atomicAdd (device-scope, coherent).
__global__ __launch_bounds__(256, 4) void k_all(
    const float* __restrict__ As, const float* __restrict__ Bs,
    const float* __restrict__ W_ct,
    const float* __restrict__ prompt, const float* __restrict__ W_cp,
    const float* __restrict__ E_layer, const float* __restrict__ E_chunk,
    const float* __restrict__ W_A, const float* __restrict__ W_B,
    const float* __restrict__ b_ct, const float* __restrict__ b_cp,
    const float* __restrict__ W_pc, const float* __restrict__ b_pc,
    const float* __restrict__ b_A, const float* __restrict__ b_B,
    float* __restrict__ ws,
    float* __restrict__ outA, float* __restrict__ outB,
    float* __restrict__ outG) {
  __shared__ float sm[4096];
  unsigned* cnt1 = (unsigned*)(ws + WS_CNT);
  unsigned* cnt2 = (unsigned*)(ws + WS_CNT + 16);
  float* fAcc = ws + WS_FACC;
  float* gatew = ws + WS_GATE;
  float* pLA = ws + WS_PLA;
  float* pLB = ws + WS_PLB;
  float* CA = ws + WS_CA;
  float* CBT = ws + WS_CBT;
  float* pFA = ws + WS_PFA;
  float* pFB = ws + WS_PFB;

  const int bx = blockIdx.x;
  const int tid = threadIdx.x;

  // ================= Phase 1: fused-independent (736 units) =============
  if (bx < 576) {                       // ---- tfeat partial (k-chunk 128)
    const int j = (bx & 3) * 256 + tid;
    const int kc = bx >> 2;
    const int kbase = kc * 128;
    const float* xsrc = (kbase < 9216) ? (As + kbase) : (Bs + (kbase - 9216));
    {
      const int i0 = tid * 4;
      const int b = i0 >> 7, kk = i0 & 127;
      *(v4f*)&sm[i0] = *(const v4f*)(xsrc + (size_t)b * 9216 + kk);
    }
    __syncthreads();
    float acc[NB] = {};
    for (int k4 = 0; k4 < 128; k4 += 4) {
      v4f xv[NB];
#pragma unroll
      for (int b = 0; b < NB; ++b) xv[b] = *(const v4f*)&sm[b * 128 + k4];
#pragma unroll
      for (int u = 0; u < 4; ++u) {
        const float w = W_ct[(size_t)(kbase + k4 + u) * NTF + j];
#pragma unroll
        for (int b = 0; b < NB; ++b) acc[b] = fmaf(xv[b][u], w, acc[b]);
      }
    }
    const int rep = kc & 3;
#pragma unroll
    for (int b = 0; b < NB; ++b)
      atomicAdd(fAcc + (size_t)(rep * NB + b) * NFUSED + j, acc[b]);
  } else if (bx < 640) {                // ---- pfeat partial (k-chunk 128)
    const int t = bx - 576;
    const int j = (t & 1) * 256 + tid;
    const int kc = t >> 1;
    const int kbase = kc * 128;
    {
      const int i0 = tid * 4;
      const int b = i0 >> 7, kk = i0 & 127;
      *(v4f*)&sm[i0] = *(const v4f*)(prompt + (size_t)b * KP + kbase + kk);
    }
    __syncthreads();
    float acc[NB] = {};
    for (int k4 = 0; k4 < 128; k4 += 4) {
      v4f xv[NB];
#pragma unroll
      for (int b = 0; b < NB; ++b) xv[b] = *(const v4f*)&sm[b * 128 + k4];
#pragma unroll
      for (int u = 0; u < 4; ++u) {
        const float w = W_cp[(size_t)(kbase + k4 + u) * NPF + j];
#pragma unroll
        for (int b = 0; b < NB; ++b) acc[b] = fmaf(xv[b][u], w, acc[b]);
      }
    }
    const int rep = kc & 3;
#pragma unroll
    for (int b = 0; b < NB; ++b)
      atomicAdd(fAcc + (size_t)(rep * NB + b) * NFUSED + NTF + j, acc[b]);
  } else if (bx < 704) {                // ---- L_A / L_B (NT stores)
    const int t = bx - 640;
    const bool isA = t < 32;
    const int tt = isA ? t : t - 32;
    const int dc = tt & 15;
    const int kh = tt >> 4;
    const float* W = (isA ? W_A : W_B) + (size_t)(NFUSED + kh * 128) * ND;
    float* pL = (isA ? pLA : pLB) + (size_t)kh * NL * ND;
    const int d = dc * 256 + tid;
    float acc[NL] = {};
    for (int kk = 0; kk < 128; ++kk) {
      const float w = W[(size_t)kk * ND + d];
      const float* el = E_layer + kh * 128 + kk;
#pragma unroll
      for (int l = 0; l < NL; ++l) acc[l] = fmaf(el[l * 256], w, acc[l]);
    }
#pragma unroll
    for (int l = 0; l < NL; ++l) nt(acc[l], pL + (size_t)l * ND + d);
  } else if (bx < 736) {                // ---- C_A / C_BT (NT stores)
    const int t = bx - 704;
    const bool isA = t < 16;
    const int tt = isA ? t : t - 16;
    const float* W = (isA ? W_A : W_B) + (size_t)(NFUSED + 256) * ND;
    for (int i = tid; i < NR * 64; i += 256) sm[i] = E_chunk[i];
    __syncthreads();
    const int d = tt * 256 + tid;
    float w[64];
#pragma unroll
    for (int k = 0; k < 64; ++k) w[k] = W[(size_t)k * ND + d];
    for (int r = 0; r < NR; ++r) {
      float s = 0.f;
#pragma unroll
      for (int k = 0; k < 64; ++k) s = fmaf(sm[r * 64 + k], w[k], s);
      if (isA) nt(s, CA + (size_t)r * ND + d);
      else     nt(s, CBT + (size_t)d * NR + r);
    }
  }
  // signal phase-1 completion
  __syncthreads();
  if (tid == 0)
    __hip_atomic_fetch_add(cnt1, 1u, __ATOMIC_RELEASE, __HIP_MEMORY_SCOPE_AGENT);

  // ================= Phase 2: F partials + gate (392 blocks) ============
  if (bx < 392) {
    if (tid == 0) {
      while (__hip_atomic_load(cnt1, __ATOMIC_RELAXED, __HIP_MEMORY_SCOPE_AGENT) < GRID)
        __builtin_amdgcn_s_sleep(16);
    }
    __syncthreads();
    if (bx < 384) {                     // ---- F partial
      const bool isA = bx < 192;
      const int t = isA ? bx : bx - 192;
      const float* W = isA ? W_A : W_B;
      float* part = isA ? pFA : pFB;
      const int dc = t & 15;
      const int kc = t >> 4;
      const int kbase = kc * 128;
      for (int i = tid; i < 1024; i += 256) {
        const int b = i >> 7, kk = i & 127;
        const int k = kbase + kk;
        float v = (k < NTF) ? b_ct[k] : b_cp[k - NTF];
#pragma unroll
        for (int rep = 0; rep < 4; ++rep)
          v += fAcc[(size_t)(rep * NB + b) * NFUSED + k];
        sm[i] = fmaxf(v, 0.f);
      }
      __syncthreads();
      const int d = dc * 256 + tid;
      float acc[NB] = {};
      for (int kk = 0; kk < 128; ++kk) {
        const float w = W[(size_t)(kbase + kk) * ND + d];
#pragma unroll
        for (int b = 0; b < NB; ++b) acc[b] = fmaf(sm[b * 128 + kk], w, acc[b]);
      }
#pragma unroll
      for (int b = 0; b < NB; ++b)
        nt(acc[b], part + (size_t)(kc * NB + b) * ND + d);
    } else {                            // ---- gate for batch b
      const int b = bx - 384;
      for (int j = tid; j < NFUSED; j += 256) {
        float v = (j < NTF) ? b_ct[j] : b_cp[j - NTF];
#pragma unroll
        for (int rep = 0; rep < 4; ++rep)
          v += fAcc[(size_t)(rep * NB + b) * NFUSED + j];
        sm[j] = fmaxf(v, 0.f);
      }
      __syncthreads();
      float acc[NL] = {};
      for (int j = tid; j < NFUSED; j += 256) {
        const float f = sm[j];
#pragma unroll
        for (int l = 0; l < NL; ++l) acc[l] = fmaf(f, W_pc[j * NL + l], acc[l]);
      }
#pragma unroll
      for (int off = 32; off > 0; off >>= 1)
#pragma unroll
        for (int l = 0; l < NL; ++l) acc[l] += __shfl_down(acc[l], off);
      const int wave = tid >> 6, lane = tid & 63;
      if (lane == 0)
#pragma unroll
        for (int l = 0; l < NL; ++l) sm[NFUSED + wave * NL + l] = acc[l];
      __syncthreads();
      if (tid < NL) {
        float s = b_pc[tid];
#pragma unroll
        for (int w = 0; w < 4; ++w) s += sm[NFUSED + w * NL + tid];
        const float g = s > 0.f ? 1.f : 0.f;
        nt(g, gatew + b * NL + tid);
        nt(g, outG + b * NL + tid);
      }
    }
  }
  // signal phase-2 completion
  __syncthreads();
  if (tid == 0)
    __hip_atomic_fetch_add(cnt2, 1u, __ATOMIC_RELEASE, __HIP_MEMORY_SCOPE_AGENT);
  if (tid == 0) {
    while (__hip_atomic_load(cnt2, __ATOMIC_RELAXED, __HIP_MEMORY_SCOPE_AGENT) < GRID)
      __builtin_amdgcn_s_sleep(16);
  }
  __syncthreads();

  // ================= Phase 3: writers (3072 units, 3 per block) =========
  for (int u = bx; u < 3072; u += GRID) {
    if (u < 1536) {                     // ---- A writer
      const int bl = u >> 3;
      const int rest = u & 7;
      const int b = bl / NL, l = bl % NL;
      const int d = (rest >> 1) * 1024 + tid * 4;
      const int r0 = (rest & 1) * 32;
      const float g = gatew[bl];
      v4f base = *(const v4f*)(b_A + d);
#pragma unroll
      for (int kc = 0; kc < FKC; ++kc)
        base += *(const v4f*)(pFA + (size_t)(kc * NB + b) * ND + d);
      base += *(const v4f*)(pLA + (size_t)l * ND + d);
      base += *(const v4f*)(pLA + (size_t)(NL + l) * ND + d);
      float* outp = outA + ((size_t)bl * NR + r0) * ND + d;
#pragma unroll 4
      for (int r = 0; r < 32; ++r) {
        const v4f c = *(const v4f*)(CA + (size_t)(r0 + r) * ND + d);
        const v4f v = (base + c) * g;
        __builtin_nontemporal_store(v, (v4f*)outp);
        outp += ND;
      }
    } else {                            // ---- B writer
      const int t = u - 1536;
      const int bl = t >> 3;
      const int b = bl / NL, l = bl % NL;
      const int dbase = (t & 7) * 512;
      __syncthreads();                  // protect sm reuse across units
      for (int dd = tid; dd < 512; dd += 256) {
        const int d = dbase + dd;
        float s = b_B[d] + pLB[(size_t)l * ND + d] + pLB[(size_t)(NL + l) * ND + d];
#pragma unroll
        for (int kc = 0; kc < FKC; ++kc)
          s += pFB[(size_t)(kc * NB + b) * ND + d];
        sm[dd] = s;
      }
      __syncthreads();
      const int dd16 = tid >> 4;
      const int r4 = (tid & 15) * 4;
#pragma unroll 4
      for (int i = 0; i < 32; ++i) {
        const int dloc = i * 16 + dd16;
        const int d = dbase + dloc;
        const v4f c = *(const v4f*)(CBT + (size_t)d * NR + r4);
        const v4f v = c + sm[dloc];
        __builtin_nontemporal_store(v, (v4f*)(outB + ((size_t)bl * ND + d) * NR + r4));
      }
    }
  }
}

extern "C" void kernel_launch(void* const* d_in, const int* in_sizes, int n_in,
                              void* d_out, int out_size, void* d_ws, size_t ws_size,
                              hipStream_t stream) {
  const float* A_small   = (const float*)d_in[0];
  const float* B_small   = (const float*)d_in[1];
  const float* prompt    = (const float*)d_in[2];
  const float* W_ct      = (const float*)d_in[3];
  const float* b_ct      = (const float*)d_in[4];
  const float* W_cp      = (const float*)d_in[5];
  const float* b_cp      = (const float*)d_in[6];
  const float* W_pc      = (const float*)d_in[7];
  const float* b_pc      = (const float*)d_in[8];
  const float* E_layer   = (const float*)d_in[9];
  const float* E_chunk   = (const float*)d_in[10];
  const float* W_A       = (const float*)d_in[11];
  const float* b_A       = (const float*)d_in[12];
  const float* W_B       = (const float*)d_in[13];
  const float* b_B       = (const float*)d_in[14];

  float* ws = (float*)d_ws;
  float* outA = (float*)d_out;                       // [192,64,4096]
  float* outB = outA + (size_t)192 * NR * ND;        // [192,4096,64]
  float* outG = outB + (size_t)192 * ND * NR;        // [192]

  // zero counters + fused accumulator
  hipMemsetAsync(ws, 0, (size_t)WS_ZERO_N * sizeof(float), stream);

  k_all<<<GRID, 256, 0, stream>>>(A_small, B_small, W_ct, prompt, W_cp,
                                  E_layer, E_chunk, W_A, W_B,
                                  b_ct, b_cp, W_pc, b_pc, b_A, b_B,
                                  ws, outA, outB, outG);
}

// Round 12
// 172.620 us; speedup vs baseline: 1.7846x; 1.7846x over previous
//
#include <hip/hip_runtime.h>

typedef float v4f __attribute__((ext_vector_type(4)));

#define NB 8        // batch
#define NL 24       // layers
#define NR 64       // chunks
#define ND 4096     // DL
#define NFUSED 1536
#define NTF 1024
#define NPF 512
#define KP 4096     // DP

#define FKC 12      // F k-chunks of 128

// workspace float offsets (R7 layout)
#define WS_FACC  0          // 4*8*1536 = 49152
#define WS_GATE  49152      // 192               -> 49344
#define WS_PLA   49344      // 2*24*4096=196608  -> 245952
#define WS_PLB   245952     // 196608            -> 442560
#define WS_CA    442560     // 262144            -> 704704
#define WS_CBT   704704     // 262144            -> 966848
#define WS_PFA   966848     // 12*8*4096=393216  -> 1360064
#define WS_PFB   1360064    // 393216            -> 1753280

// =====================================================================
// K1: 736 blocks (R10 verbatim)
//   [0,576)   tfeat partial (k-chunk 128) -> atomicAdd fAcc[kc&3][b][j]
//   [576,640) pfeat partial (k-chunk 128) -> atomicAdd fAcc[kc&3][b][1024+j]
//   [640,704) L_A / L_B   (16 d-chunks x 2 k-halves x 2 mats)
//   [704,736) C_A / C_BT  (16 d-chunks x 2 mats)
// =====================================================================
__global__ __launch_bounds__(256) void k_indep(
    const float* __restrict__ As, const float* __restrict__ Bs,
    const float* __restrict__ W_ct,
    const float* __restrict__ prompt, const float* __restrict__ W_cp,
    const float* __restrict__ E_layer, const float* __restrict__ E_chunk,
    const float* __restrict__ W_A, const float* __restrict__ W_B,
    float* __restrict__ fAcc,
    float* __restrict__ pLA, float* __restrict__ pLB,
    float* __restrict__ CA, float* __restrict__ CBT) {
  __shared__ float e[NR * 64];
  const int bx = blockIdx.x;
  const int tid = threadIdx.x;

  if (bx < 576) {                       // ---- tfeat partial (k-chunk 128)
    const int j = (bx & 3) * 256 + tid;
    const int kc = bx >> 2;             // [0,144)
    const int kbase = kc * 128;
    const float* xsrc = (kbase < 9216) ? (As + kbase) : (Bs + (kbase - 9216));
    {
      const int i0 = tid * 4;           // 256 threads x v4f = 1024 floats
      const int b = i0 >> 7, kk = i0 & 127;
      *(v4f*)&e[i0] = *(const v4f*)(xsrc + (size_t)b * 9216 + kk);
    }
    __syncthreads();
    float acc[NB] = {};
    for (int k4 = 0; k4 < 128; k4 += 4) {
      v4f xv[NB];
#pragma unroll
      for (int b = 0; b < NB; ++b) xv[b] = *(const v4f*)&e[b * 128 + k4];
#pragma unroll
      for (int u = 0; u < 4; ++u) {
        const float w = W_ct[(size_t)(kbase + k4 + u) * NTF + j];
#pragma unroll
        for (int b = 0; b < NB; ++b) acc[b] = fmaf(xv[b][u], w, acc[b]);
      }
    }
    const int rep = kc & 3;
#pragma unroll
    for (int b = 0; b < NB; ++b)
      atomicAdd(fAcc + (size_t)(rep * NB + b) * NFUSED + j, acc[b]);
  } else if (bx < 640) {                // ---- pfeat partial (k-chunk 128)
    const int t = bx - 576;
    const int j = (t & 1) * 256 + tid;
    const int kc = t >> 1;              // [0,32)
    const int kbase = kc * 128;
    {
      const int i0 = tid * 4;
      const int b = i0 >> 7, kk = i0 & 127;
      *(v4f*)&e[i0] = *(const v4f*)(prompt + (size_t)b * KP + kbase + kk);
    }
    __syncthreads();
    float acc[NB] = {};
    for (int k4 = 0; k4 < 128; k4 += 4) {
      v4f xv[NB];
#pragma unroll
      for (int b = 0; b < NB; ++b) xv[b] = *(const v4f*)&e[b * 128 + k4];
#pragma unroll
      for (int u = 0; u < 4; ++u) {
        const float w = W_cp[(size_t)(kbase + k4 + u) * NPF + j];
#pragma unroll
        for (int b = 0; b < NB; ++b) acc[b] = fmaf(xv[b][u], w, acc[b]);
      }
    }
    const int rep = kc & 3;
#pragma unroll
    for (int b = 0; b < NB; ++b)
      atomicAdd(fAcc + (size_t)(rep * NB + b) * NFUSED + NTF + j, acc[b]);
  } else if (bx < 704) {                // ---- L_A / L_B (split-K 2 halves)
    const int t = bx - 640;
    const bool isA = t < 32;
    const int tt = isA ? t : t - 32;
    const int dc = tt & 15;
    const int kh = tt >> 4;             // 0 or 1
    const float* W = (isA ? W_A : W_B) + (size_t)(NFUSED + kh * 128) * ND;
    float* pL = (isA ? pLA : pLB) + (size_t)kh * NL * ND;
    const int d = dc * 256 + tid;
    float acc[NL] = {};
    for (int kk = 0; kk < 128; ++kk) {
      const float w = W[(size_t)kk * ND + d];
      const float* el = E_layer + kh * 128 + kk;
#pragma unroll
      for (int l = 0; l < NL; ++l) acc[l] = fmaf(el[l * 256], w, acc[l]);
    }
#pragma unroll
    for (int l = 0; l < NL; ++l) pL[(size_t)l * ND + d] = acc[l];
  } else {                              // ---- C_A / C_BT
    const int t = bx - 704;
    const bool isA = t < 16;
    const int tt = isA ? t : t - 16;
    const float* W = (isA ? W_A : W_B) + (size_t)(NFUSED + 256) * ND;
    for (int i = tid; i < NR * 64; i += 256) e[i] = E_chunk[i];
    __syncthreads();
    const int d = tt * 256 + tid;
    float w[64];
#pragma unroll
    for (int k = 0; k < 64; ++k) w[k] = W[(size_t)k * ND + d];
    for (int r = 0; r < NR; ++r) {
      float s = 0.f;
#pragma unroll
      for (int k = 0; k < 64; ++k) s = fmaf(e[r * 64 + k], w[k], s);
      if (isA) CA[(size_t)r * ND + d] = s;
      else     CBT[(size_t)d * NR + r] = s;
    }
  }
}

// =====================================================================
// K3: F partials + gate — 392 blocks (R10 verbatim)
// =====================================================================
__global__ __launch_bounds__(256) void k_dep(
    const float* __restrict__ fAcc,
    const float* __restrict__ b_ct, const float* __restrict__ b_cp,
    const float* __restrict__ W_A, const float* __restrict__ W_B,
    const float* __restrict__ W_pc, const float* __restrict__ b_pc,
    float* __restrict__ pFA, float* __restrict__ pFB,
    float* __restrict__ gate_ws, float* __restrict__ gate_out) {
  __shared__ float sm[1664];
  const int bx = blockIdx.x;
  const int tid = threadIdx.x;

  if (bx < 384) {                       // ---- F partial
    const bool isA = bx < 192;
    const int t = isA ? bx : bx - 192;
    const float* W = isA ? W_A : W_B;
    float* part = isA ? pFA : pFB;
    const int dc = t & 15;
    const int kc = t >> 4;
    const int kbase = kc * 128;

    for (int i = tid; i < 1024; i += 256) {
      const int b = i >> 7, kk = i & 127;
      const int k = kbase + kk;
      float v = (k < NTF) ? b_ct[k] : b_cp[k - NTF];
#pragma unroll
      for (int rep = 0; rep < 4; ++rep)
        v += fAcc[(size_t)(rep * NB + b) * NFUSED + k];
      sm[i] = fmaxf(v, 0.f);
    }
    __syncthreads();

    const int d = dc * 256 + tid;
    float acc[NB] = {};
    for (int kk = 0; kk < 128; ++kk) {
      const float w = W[(size_t)(kbase + kk) * ND + d];
#pragma unroll
      for (int b = 0; b < NB; ++b) acc[b] = fmaf(sm[b * 128 + kk], w, acc[b]);
    }
#pragma unroll
    for (int b = 0; b < NB; ++b)
      part[(size_t)(kc * NB + b) * ND + d] = acc[b];
  } else {                              // ---- gate for batch b
    const int b = bx - 384;
    for (int j = tid; j < NFUSED; j += 256) {
      float v = (j < NTF) ? b_ct[j] : b_cp[j - NTF];
#pragma unroll
      for (int rep = 0; rep < 4; ++rep)
        v += fAcc[(size_t)(rep * NB + b) * NFUSED + j];
      sm[j] = fmaxf(v, 0.f);
    }
    __syncthreads();
    float acc[NL] = {};
    for (int j = tid; j < NFUSED; j += 256) {
      const float f = sm[j];
#pragma unroll
      for (int l = 0; l < NL; ++l) acc[l] = fmaf(f, W_pc[j * NL + l], acc[l]);
    }
#pragma unroll
    for (int off = 32; off > 0; off >>= 1)
#pragma unroll
      for (int l = 0; l < NL; ++l) acc[l] += __shfl_down(acc[l], off);
    const int wave = tid >> 6, lane = tid & 63;
    if (lane == 0)
#pragma unroll
      for (int l = 0; l < NL; ++l) sm[NFUSED + wave * NL + l] = acc[l];
    __syncthreads();
    if (tid < NL) {
      float s = b_pc[tid];
#pragma unroll
      for (int w = 0; w < 4; ++w) s += sm[NFUSED + w * NL + tid];
      const float g = s > 0.f ? 1.f : 0.f;
      gate_ws[b * NL + tid] = g;
      gate_out[b * NL + tid] = g;
    }
  }
}

// =====================================================================
// K4: writers — 3072 blocks (R10 structure, PLAIN stores instead of NT)
// =====================================================================
__global__ __launch_bounds__(256) void k_out(
    const float* __restrict__ pFA, const float* __restrict__ pFB,
    const float* __restrict__ b_A, const float* __restrict__ b_B,
    const float* __restrict__ pLA, const float* __restrict__ pLB,
    const float* __restrict__ CA, const float* __restrict__ CBT,
    const float* __restrict__ gate,
    float* __restrict__ outA, float* __restrict__ outB) {
  __shared__ float sbase[512];
  const int bx = blockIdx.x;
  const int tid = threadIdx.x;
  if (bx < 1536) {                      // ---- A writer
    const int bl = bx >> 3;
    const int rest = bx & 7;
    const int b = bl / NL, l = bl % NL;
    const int d = (rest >> 1) * 1024 + tid * 4;
    const int r0 = (rest & 1) * 32;
    const float g = gate[bl];
    v4f base = *(const v4f*)(b_A + d);
#pragma unroll
    for (int kc = 0; kc < FKC; ++kc)
      base += *(const v4f*)(pFA + (size_t)(kc * NB + b) * ND + d);
    base += *(const v4f*)(pLA + (size_t)l * ND + d);
    base += *(const v4f*)(pLA + (size_t)(NL + l) * ND + d);
    float* outp = outA + ((size_t)bl * NR + r0) * ND + d;
#pragma unroll 4
    for (int r = 0; r < 32; ++r) {
      const v4f c = *(const v4f*)(CA + (size_t)(r0 + r) * ND + d);
      const v4f v = (base + c) * g;
      *(v4f*)outp = v;
      outp += ND;
    }
  } else {                              // ---- B writer
    const int t = bx - 1536;
    const int bl = t >> 3;
    const int b = bl / NL, l = bl % NL;
    const int dbase = (t & 7) * 512;
    for (int dd = tid; dd < 512; dd += 256) {
      const int d = dbase + dd;
      float s = b_B[d] + pLB[(size_t)l * ND + d] + pLB[(size_t)(NL + l) * ND + d];
#pragma unroll
      for (int kc = 0; kc < FKC; ++kc)
        s += pFB[(size_t)(kc * NB + b) * ND + d];
      sbase[dd] = s;
    }
    __syncthreads();
    const int dd16 = tid >> 4;
    const int r4 = (tid & 15) * 4;
#pragma unroll 4
    for (int i = 0; i < 32; ++i) {
      const int dloc = i * 16 + dd16;
      const int d = dbase + dloc;
      const v4f c = *(const v4f*)(CBT + (size_t)d * NR + r4);
      const v4f v = c + sbase[dloc];
      *(v4f*)(outB + ((size_t)bl * ND + d) * NR + r4) = v;
    }
  }
}

extern "C" void kernel_launch(void* const* d_in, const int* in_sizes, int n_in,
                              void* d_out, int out_size, void* d_ws, size_t ws_size,
                              hipStream_t stream) {
  const float* A_small   = (const float*)d_in[0];
  const float* B_small   = (const float*)d_in[1];
  const float* prompt    = (const float*)d_in[2];
  const float* W_ct      = (const float*)d_in[3];
  const float* b_ct      = (const float*)d_in[4];
  const float* W_cp      = (const float*)d_in[5];
  const float* b_cp      = (const float*)d_in[6];
  const float* W_pc      = (const float*)d_in[7];
  const float* b_pc      = (const float*)d_in[8];
  const float* E_layer   = (const float*)d_in[9];
  const float* E_chunk   = (const float*)d_in[10];
  const float* W_A       = (const float*)d_in[11];
  const float* b_A       = (const float*)d_in[12];
  const float* W_B       = (const float*)d_in[13];
  const float* b_B       = (const float*)d_in[14];

  float* ws    = (float*)d_ws;
  float* fAcc  = ws + WS_FACC;
  float* gatew = ws + WS_GATE;
  float* pLA   = ws + WS_PLA;
  float* pLB   = ws + WS_PLB;
  float* CA    = ws + WS_CA;
  float* CBT   = ws + WS_CBT;
  float* pFA   = ws + WS_PFA;
  float* pFB   = ws + WS_PFB;

  float* outA = (float*)d_out;                       // [192,64,4096]
  float* outB = outA + (size_t)192 * NR * ND;        // [192,4096,64]
  float* outG = outB + (size_t)192 * ND * NR;        // [192]

  // zero the 4-replica fused accumulator
  hipMemsetAsync(fAcc, 0, (size_t)4 * NB * NFUSED * sizeof(float), stream);

  k_indep<<<736, 256, 0, stream>>>(A_small, B_small, W_ct, prompt, W_cp,
                                   E_layer, E_chunk, W_A, W_B,
                                   fAcc, pLA, pLB, CA, CBT);
  k_dep<<<392, 256, 0, stream>>>(fAcc, b_ct, b_cp, W_A, W_B,
                                 W_pc, b_pc, pFA, pFB, gatew, outG);
  k_out<<<3072, 256, 0, stream>>>(pFA, pFB, b_A, b_B, pLA, pLB, CA, CBT,
                                  gatew, outA, outB);
}

// Round 13
// 149.663 us; speedup vs baseline: 2.0583x; 1.1534x over previous
//
#include <hip/hip_runtime.h>

typedef float v4f __attribute__((ext_vector_type(4)));

#define NB 8        // batch
#define NL 24       // layers
#define NR 64       // chunks
#define ND 4096     // DL
#define NFUSED 1536
#define NTF 1024
#define NPF 512
#define KP 4096     // DP

#define FKC 12      // F k-chunks of 128

// workspace float offsets (R7 layout)
#define WS_FACC  0          // 4*8*1536 = 49152
#define WS_GATE  49152      // 192               -> 49344
#define WS_PLA   49344      // 2*24*4096=196608  -> 245952
#define WS_PLB   245952     // 196608            -> 442560
#define WS_CA    442560     // 262144            -> 704704
#define WS_CBT   704704     // 262144            -> 966848
#define WS_PFA   966848     // 12*8*4096=393216  -> 1360064
#define WS_PFB   1360064    // 393216            -> 1753280

__device__ __forceinline__ void nts(float v, float* p) {
  __builtin_nontemporal_store(v, p);
}

// =====================================================================
// K1: 736 blocks (R10 structure; intermediate stores are NT)
//   [0,576)   tfeat partial (k-chunk 128) -> atomicAdd fAcc[kc&3][b][j]
//   [576,640) pfeat partial (k-chunk 128) -> atomicAdd fAcc[kc&3][b][1024+j]
//   [640,704) L_A / L_B   (16 d-chunks x 2 k-halves x 2 mats)
//   [704,736) C_A / C_BT  (16 d-chunks x 2 mats)
// =====================================================================
__global__ __launch_bounds__(256) void k_indep(
    const float* __restrict__ As, const float* __restrict__ Bs,
    const float* __restrict__ W_ct,
    const float* __restrict__ prompt, const float* __restrict__ W_cp,
    const float* __restrict__ E_layer, const float* __restrict__ E_chunk,
    const float* __restrict__ W_A, const float* __restrict__ W_B,
    float* __restrict__ fAcc,
    float* __restrict__ pLA, float* __restrict__ pLB,
    float* __restrict__ CA, float* __restrict__ CBT) {
  __shared__ float e[NR * 64];
  const int bx = blockIdx.x;
  const int tid = threadIdx.x;

  if (bx < 576) {                       // ---- tfeat partial (k-chunk 128)
    const int j = (bx & 3) * 256 + tid;
    const int kc = bx >> 2;             // [0,144)
    const int kbase = kc * 128;
    const float* xsrc = (kbase < 9216) ? (As + kbase) : (Bs + (kbase - 9216));
    {
      const int i0 = tid * 4;           // 256 threads x v4f = 1024 floats
      const int b = i0 >> 7, kk = i0 & 127;
      *(v4f*)&e[i0] = *(const v4f*)(xsrc + (size_t)b * 9216 + kk);
    }
    __syncthreads();
    float acc[NB] = {};
    for (int k4 = 0; k4 < 128; k4 += 4) {
      v4f xv[NB];
#pragma unroll
      for (int b = 0; b < NB; ++b) xv[b] = *(const v4f*)&e[b * 128 + k4];
#pragma unroll
      for (int u = 0; u < 4; ++u) {
        const float w = W_ct[(size_t)(kbase + k4 + u) * NTF + j];
#pragma unroll
        for (int b = 0; b < NB; ++b) acc[b] = fmaf(xv[b][u], w, acc[b]);
      }
    }
    const int rep = kc & 3;
#pragma unroll
    for (int b = 0; b < NB; ++b)
      atomicAdd(fAcc + (size_t)(rep * NB + b) * NFUSED + j, acc[b]);
  } else if (bx < 640) {                // ---- pfeat partial (k-chunk 128)
    const int t = bx - 576;
    const int j = (t & 1) * 256 + tid;
    const int kc = t >> 1;              // [0,32)
    const int kbase = kc * 128;
    {
      const int i0 = tid * 4;
      const int b = i0 >> 7, kk = i0 & 127;
      *(v4f*)&e[i0] = *(const v4f*)(prompt + (size_t)b * KP + kbase + kk);
    }
    __syncthreads();
    float acc[NB] = {};
    for (int k4 = 0; k4 < 128; k4 += 4) {
      v4f xv[NB];
#pragma unroll
      for (int b = 0; b < NB; ++b) xv[b] = *(const v4f*)&e[b * 128 + k4];
#pragma unroll
      for (int u = 0; u < 4; ++u) {
        const float w = W_cp[(size_t)(kbase + k4 + u) * NPF + j];
#pragma unroll
        for (int b = 0; b < NB; ++b) acc[b] = fmaf(xv[b][u], w, acc[b]);
      }
    }
    const int rep = kc & 3;
#pragma unroll
    for (int b = 0; b < NB; ++b)
      atomicAdd(fAcc + (size_t)(rep * NB + b) * NFUSED + NTF + j, acc[b]);
  } else if (bx < 704) {                // ---- L_A / L_B (split-K 2 halves)
    const int t = bx - 640;
    const bool isA = t < 32;
    const int tt = isA ? t : t - 32;
    const int dc = tt & 15;
    const int kh = tt >> 4;             // 0 or 1
    const float* W = (isA ? W_A : W_B) + (size_t)(NFUSED + kh * 128) * ND;
    float* pL = (isA ? pLA : pLB) + (size_t)kh * NL * ND;
    const int d = dc * 256 + tid;
    float acc[NL] = {};
    for (int kk = 0; kk < 128; ++kk) {
      const float w = W[(size_t)kk * ND + d];
      const float* el = E_layer + kh * 128 + kk;
#pragma unroll
      for (int l = 0; l < NL; ++l) acc[l] = fmaf(el[l * 256], w, acc[l]);
    }
#pragma unroll
    for (int l = 0; l < NL; ++l) nts(acc[l], pL + (size_t)l * ND + d);
  } else {                              // ---- C_A / C_BT
    const int t = bx - 704;
    const bool isA = t < 16;
    const int tt = isA ? t : t - 16;
    const float* W = (isA ? W_A : W_B) + (size_t)(NFUSED + 256) * ND;
    for (int i = tid; i < NR * 64; i += 256) e[i] = E_chunk[i];
    __syncthreads();
    const int d = tt * 256 + tid;
    float w[64];
#pragma unroll
    for (int k = 0; k < 64; ++k) w[k] = W[(size_t)k * ND + d];
    for (int r = 0; r < NR; ++r) {
      float s = 0.f;
#pragma unroll
      for (int k = 0; k < 64; ++k) s = fmaf(e[r * 64 + k], w[k], s);
      if (isA) nts(s, CA + (size_t)r * ND + d);
      else     nts(s, CBT + (size_t)d * NR + r);
    }
  }
}

// =====================================================================
// K3: F partials + gate — 392 blocks (R10 structure; pF stores NT)
// =====================================================================
__global__ __launch_bounds__(256) void k_dep(
    const float* __restrict__ fAcc,
    const float* __restrict__ b_ct, const float* __restrict__ b_cp,
    const float* __restrict__ W_A, const float* __restrict__ W_B,
    const float* __restrict__ W_pc, const float* __restrict__ b_pc,
    float* __restrict__ pFA, float* __restrict__ pFB,
    float* __restrict__ gate_ws, float* __restrict__ gate_out) {
  __shared__ float sm[1664];
  const int bx = blockIdx.x;
  const int tid = threadIdx.x;

  if (bx < 384) {                       // ---- F partial
    const bool isA = bx < 192;
    const int t = isA ? bx : bx - 192;
    const float* W = isA ? W_A : W_B;
    float* part = isA ? pFA : pFB;
    const int dc = t & 15;
    const int kc = t >> 4;
    const int kbase = kc * 128;

    for (int i = tid; i < 1024; i += 256) {
      const int b = i >> 7, kk = i & 127;
      const int k = kbase + kk;
      float v = (k < NTF) ? b_ct[k] : b_cp[k - NTF];
#pragma unroll
      for (int rep = 0; rep < 4; ++rep)
        v += fAcc[(size_t)(rep * NB + b) * NFUSED + k];
      sm[i] = fmaxf(v, 0.f);
    }
    __syncthreads();

    const int d = dc * 256 + tid;
    float acc[NB] = {};
    for (int kk = 0; kk < 128; ++kk) {
      const float w = W[(size_t)(kbase + kk) * ND + d];
#pragma unroll
      for (int b = 0; b < NB; ++b) acc[b] = fmaf(sm[b * 128 + kk], w, acc[b]);
    }
#pragma unroll
    for (int b = 0; b < NB; ++b)
      nts(acc[b], part + (size_t)(kc * NB + b) * ND + d);
  } else {                              // ---- gate for batch b
    const int b = bx - 384;
    for (int j = tid; j < NFUSED; j += 256) {
      float v = (j < NTF) ? b_ct[j] : b_cp[j - NTF];
#pragma unroll
      for (int rep = 0; rep < 4; ++rep)
        v += fAcc[(size_t)(rep * NB + b) * NFUSED + j];
      sm[j] = fmaxf(v, 0.f);
    }
    __syncthreads();
    float acc[NL] = {};
    for (int j = tid; j < NFUSED; j += 256) {
      const float f = sm[j];
#pragma unroll
      for (int l = 0; l < NL; ++l) acc[l] = fmaf(f, W_pc[j * NL + l], acc[l]);
    }
#pragma unroll
    for (int off = 32; off > 0; off >>= 1)
#pragma unroll
      for (int l = 0; l < NL; ++l) acc[l] += __shfl_down(acc[l], off);
    const int wave = tid >> 6, lane = tid & 63;
    if (lane == 0)
#pragma unroll
      for (int l = 0; l < NL; ++l) sm[NFUSED + wave * NL + l] = acc[l];
    __syncthreads();
    if (tid < NL) {
      float s = b_pc[tid];
#pragma unroll
      for (int w = 0; w < 4; ++w) s += sm[NFUSED + w * NL + tid];
      const float g = s > 0.f ? 1.f : 0.f;
      gate_ws[b * NL + tid] = g;
      gate_out[b * NL + tid] = g;
    }
  }
}

// =====================================================================
// K4: writers — 3072 blocks (R10 verbatim, NT output stores)
// =====================================================================
__global__ __launch_bounds__(256) void k_out(
    const float* __restrict__ pFA, const float* __restrict__ pFB,
    const float* __restrict__ b_A, const float* __restrict__ b_B,
    const float* __restrict__ pLA, const float* __restrict__ pLB,
    const float* __restrict__ CA, const float* __restrict__ CBT,
    const float* __restrict__ gate,
    float* __restrict__ outA, float* __restrict__ outB) {
  __shared__ float sbase[512];
  const int bx = blockIdx.x;
  const int tid = threadIdx.x;
  if (bx < 1536) {                      // ---- A writer
    const int bl = bx >> 3;
    const int rest = bx & 7;
    const int b = bl / NL, l = bl % NL;
    const int d = (rest >> 1) * 1024 + tid * 4;
    const int r0 = (rest & 1) * 32;
    const float g = gate[bl];
    v4f base = *(const v4f*)(b_A + d);
#pragma unroll
    for (int kc = 0; kc < FKC; ++kc)
      base += *(const v4f*)(pFA + (size_t)(kc * NB + b) * ND + d);
    base += *(const v4f*)(pLA + (size_t)l * ND + d);
    base += *(const v4f*)(pLA + (size_t)(NL + l) * ND + d);
    float* outp = outA + ((size_t)bl * NR + r0) * ND + d;
#pragma unroll 4
    for (int r = 0; r < 32; ++r) {
      const v4f c = *(const v4f*)(CA + (size_t)(r0 + r) * ND + d);
      const v4f v = (base + c) * g;
      __builtin_nontemporal_store(v, (v4f*)outp);
      outp += ND;
    }
  } else {                              // ---- B writer
    const int t = bx - 1536;
    const int bl = t >> 3;
    const int b = bl / NL, l = bl % NL;
    const int dbase = (t & 7) * 512;
    for (int dd = tid; dd < 512; dd += 256) {
      const int d = dbase + dd;
      float s = b_B[d] + pLB[(size_t)l * ND + d] + pLB[(size_t)(NL + l) * ND + d];
#pragma unroll
      for (int kc = 0; kc < FKC; ++kc)
        s += pFB[(size_t)(kc * NB + b) * ND + d];
      sbase[dd] = s;
    }
    __syncthreads();
    const int dd16 = tid >> 4;
    const int r4 = (tid & 15) * 4;
#pragma unroll 4
    for (int i = 0; i < 32; ++i) {
      const int dloc = i * 16 + dd16;
      const int d = dbase + dloc;
      const v4f c = *(const v4f*)(CBT + (size_t)d * NR + r4);
      const v4f v = c + sbase[dloc];
      __builtin_nontemporal_store(v, (v4f*)(outB + ((size_t)bl * ND + d) * NR + r4));
    }
  }
}

extern "C" void kernel_launch(void* const* d_in, const int* in_sizes, int n_in,
                              void* d_out, int out_size, void* d_ws, size_t ws_size,
                              hipStream_t stream) {
  const float* A_small   = (const float*)d_in[0];
  const float* B_small   = (const float*)d_in[1];
  const float* prompt    = (const float*)d_in[2];
  const float* W_ct      = (const float*)d_in[3];
  const float* b_ct      = (const float*)d_in[4];
  const float* W_cp      = (const float*)d_in[5];
  const float* b_cp      = (const float*)d_in[6];
  const float* W_pc      = (const float*)d_in[7];
  const float* b_pc      = (const float*)d_in[8];
  const float* E_layer   = (const float*)d_in[9];
  const float* E_chunk   = (const float*)d_in[10];
  const float* W_A       = (const float*)d_in[11];
  const float* b_A       = (const float*)d_in[12];
  const float* W_B       = (const float*)d_in[13];
  const float* b_B       = (const float*)d_in[14];

  float* ws    = (float*)d_ws;
  float* fAcc  = ws + WS_FACC;
  float* gatew = ws + WS_GATE;
  float* pLA   = ws + WS_PLA;
  float* pLB   = ws + WS_PLB;
  float* CA    = ws + WS_CA;
  float* CBT   = ws + WS_CBT;
  float* pFA   = ws + WS_PFA;
  float* pFB   = ws + WS_PFB;

  float* outA = (float*)d_out;                       // [192,64,4096]
  float* outB = outA + (size_t)192 * NR * ND;        // [192,4096,64]
  float* outG = outB + (size_t)192 * ND * NR;        // [192]

  // zero the 4-replica fused accumulator
  hipMemsetAsync(fAcc, 0, (size_t)4 * NB * NFUSED * sizeof(float), stream);

  k_indep<<<736, 256, 0, stream>>>(A_small, B_small, W_ct, prompt, W_cp,
                                   E_layer, E_chunk, W_A, W_B,
                                   fAcc, pLA, pLB, CA, CBT);
  k_dep<<<392, 256, 0, stream>>>(fAcc, b_ct, b_cp, W_A, W_B,
                                 W_pc, b_pc, pFA, pFB, gatew, outG);
  k_out<<<3072, 256, 0, stream>>>(pFA, pFB, b_A, b_B, pLA, pLB, CA, CBT,
                                  gatew, outA, outB);
}

// Round 14
// 143.311 us; speedup vs baseline: 2.1496x; 1.0443x over previous
//
#include <hip/hip_runtime.h>

typedef float v4f __attribute__((ext_vector_type(4)));

#define NB 8        // batch
#define NL 24       // layers
#define NR 64       // chunks
#define ND 4096     // DL
#define NFUSED 1536
#define NTF 1024
#define NPF 512
#define KP 4096     // DP

#define FKC 12      // F k-chunks of 128

// workspace float offsets (R7 layout)
#define WS_FACC  0          // 4*8*1536 = 49152
#define WS_GATE  49152      // 192               -> 49344
#define WS_PLA   49344      // 2*24*4096=196608  -> 245952
#define WS_PLB   245952     // 196608            -> 442560
#define WS_CA    442560     // 262144            -> 704704
#define WS_CBT   704704     // 262144            -> 966848
#define WS_PFA   966848     // 12*8*4096=393216  -> 1360064
#define WS_PFB   1360064    // 393216            -> 1753280

// =====================================================================
// K1: 736 blocks (R10 verbatim)
// =====================================================================
__global__ __launch_bounds__(256) void k_indep(
    const float* __restrict__ As, const float* __restrict__ Bs,
    const float* __restrict__ W_ct,
    const float* __restrict__ prompt, const float* __restrict__ W_cp,
    const float* __restrict__ E_layer, const float* __restrict__ E_chunk,
    const float* __restrict__ W_A, const float* __restrict__ W_B,
    float* __restrict__ fAcc,
    float* __restrict__ pLA, float* __restrict__ pLB,
    float* __restrict__ CA, float* __restrict__ CBT) {
  __shared__ float e[NR * 64];
  const int bx = blockIdx.x;
  const int tid = threadIdx.x;

  if (bx < 576) {                       // ---- tfeat partial (k-chunk 128)
    const int j = (bx & 3) * 256 + tid;
    const int kc = bx >> 2;             // [0,144)
    const int kbase = kc * 128;
    const float* xsrc = (kbase < 9216) ? (As + kbase) : (Bs + (kbase - 9216));
    {
      const int i0 = tid * 4;
      const int b = i0 >> 7, kk = i0 & 127;
      *(v4f*)&e[i0] = *(const v4f*)(xsrc + (size_t)b * 9216 + kk);
    }
    __syncthreads();
    float acc[NB] = {};
    for (int k4 = 0; k4 < 128; k4 += 4) {
      v4f xv[NB];
#pragma unroll
      for (int b = 0; b < NB; ++b) xv[b] = *(const v4f*)&e[b * 128 + k4];
#pragma unroll
      for (int u = 0; u < 4; ++u) {
        const float w = W_ct[(size_t)(kbase + k4 + u) * NTF + j];
#pragma unroll
        for (int b = 0; b < NB; ++b) acc[b] = fmaf(xv[b][u], w, acc[b]);
      }
    }
    const int rep = kc & 3;
#pragma unroll
    for (int b = 0; b < NB; ++b)
      atomicAdd(fAcc + (size_t)(rep * NB + b) * NFUSED + j, acc[b]);
  } else if (bx < 640) {                // ---- pfeat partial (k-chunk 128)
    const int t = bx - 576;
    const int j = (t & 1) * 256 + tid;
    const int kc = t >> 1;              // [0,32)
    const int kbase = kc * 128;
    {
      const int i0 = tid * 4;
      const int b = i0 >> 7, kk = i0 & 127;
      *(v4f*)&e[i0] = *(const v4f*)(prompt + (size_t)b * KP + kbase + kk);
    }
    __syncthreads();
    float acc[NB] = {};
    for (int k4 = 0; k4 < 128; k4 += 4) {
      v4f xv[NB];
#pragma unroll
      for (int b = 0; b < NB; ++b) xv[b] = *(const v4f*)&e[b * 128 + k4];
#pragma unroll
      for (int u = 0; u < 4; ++u) {
        const float w = W_cp[(size_t)(kbase + k4 + u) * NPF + j];
#pragma unroll
        for (int b = 0; b < NB; ++b) acc[b] = fmaf(xv[b][u], w, acc[b]);
      }
    }
    const int rep = kc & 3;
#pragma unroll
    for (int b = 0; b < NB; ++b)
      atomicAdd(fAcc + (size_t)(rep * NB + b) * NFUSED + NTF + j, acc[b]);
  } else if (bx < 704) {                // ---- L_A / L_B (split-K 2 halves)
    const int t = bx - 640;
    const bool isA = t < 32;
    const int tt = isA ? t : t - 32;
    const int dc = tt & 15;
    const int kh = tt >> 4;
    const float* W = (isA ? W_A : W_B) + (size_t)(NFUSED + kh * 128) * ND;
    float* pL = (isA ? pLA : pLB) + (size_t)kh * NL * ND;
    const int d = dc * 256 + tid;
    float acc[NL] = {};
    for (int kk = 0; kk < 128; ++kk) {
      const float w = W[(size_t)kk * ND + d];
      const float* el = E_layer + kh * 128 + kk;
#pragma unroll
      for (int l = 0; l < NL; ++l) acc[l] = fmaf(el[l * 256], w, acc[l]);
    }
#pragma unroll
    for (int l = 0; l < NL; ++l) pL[(size_t)l * ND + d] = acc[l];
  } else {                              // ---- C_A / C_BT
    const int t = bx - 704;
    const bool isA = t < 16;
    const int tt = isA ? t : t - 16;
    const float* W = (isA ? W_A : W_B) + (size_t)(NFUSED + 256) * ND;
    for (int i = tid; i < NR * 64; i += 256) e[i] = E_chunk[i];
    __syncthreads();
    const int d = tt * 256 + tid;
    float w[64];
#pragma unroll
    for (int k = 0; k < 64; ++k) w[k] = W[(size_t)k * ND + d];
    for (int r = 0; r < NR; ++r) {
      float s = 0.f;
#pragma unroll
      for (int k = 0; k < 64; ++k) s = fmaf(e[r * 64 + k], w[k], s);
      if (isA) CA[(size_t)r * ND + d] = s;
      else     CBT[(size_t)d * NR + r] = s;
    }
  }
}

// =====================================================================
// K3: F partials + gate — 392 blocks (R10 verbatim)
// =====================================================================
__global__ __launch_bounds__(256) void k_dep(
    const float* __restrict__ fAcc,
    const float* __restrict__ b_ct, const float* __restrict__ b_cp,
    const float* __restrict__ W_A, const float* __restrict__ W_B,
    const float* __restrict__ W_pc, const float* __restrict__ b_pc,
    float* __restrict__ pFA, float* __restrict__ pFB,
    float* __restrict__ gate_ws, float* __restrict__ gate_out) {
  __shared__ float sm[1664];
  const int bx = blockIdx.x;
  const int tid = threadIdx.x;

  if (bx < 384) {                       // ---- F partial
    const bool isA = bx < 192;
    const int t = isA ? bx : bx - 192;
    const float* W = isA ? W_A : W_B;
    float* part = isA ? pFA : pFB;
    const int dc = t & 15;
    const int kc = t >> 4;
    const int kbase = kc * 128;

    for (int i = tid; i < 1024; i += 256) {
      const int b = i >> 7, kk = i & 127;
      const int k = kbase + kk;
      float v = (k < NTF) ? b_ct[k] : b_cp[k - NTF];
#pragma unroll
      for (int rep = 0; rep < 4; ++rep)
        v += fAcc[(size_t)(rep * NB + b) * NFUSED + k];
      sm[i] = fmaxf(v, 0.f);
    }
    __syncthreads();

    const int d = dc * 256 + tid;
    float acc[NB] = {};
    for (int kk = 0; kk < 128; ++kk) {
      const float w = W[(size_t)(kbase + kk) * ND + d];
#pragma unroll
      for (int b = 0; b < NB; ++b) acc[b] = fmaf(sm[b * 128 + kk], w, acc[b]);
    }
#pragma unroll
    for (int b = 0; b < NB; ++b)
      part[(size_t)(kc * NB + b) * ND + d] = acc[b];
  } else {                              // ---- gate for batch b
    const int b = bx - 384;
    for (int j = tid; j < NFUSED; j += 256) {
      float v = (j < NTF) ? b_ct[j] : b_cp[j - NTF];
#pragma unroll
      for (int rep = 0; rep < 4; ++rep)
        v += fAcc[(size_t)(rep * NB + b) * NFUSED + j];
      sm[j] = fmaxf(v, 0.f);
    }
    __syncthreads();
    float acc[NL] = {};
    for (int j = tid; j < NFUSED; j += 256) {
      const float f = sm[j];
#pragma unroll
      for (int l = 0; l < NL; ++l) acc[l] = fmaf(f, W_pc[j * NL + l], acc[l]);
    }
#pragma unroll
    for (int off = 32; off > 0; off >>= 1)
#pragma unroll
      for (int l = 0; l < NL; ++l) acc[l] += __shfl_down(acc[l], off);
    const int wave = tid >> 6, lane = tid & 63;
    if (lane == 0)
#pragma unroll
      for (int l = 0; l < NL; ++l) sm[NFUSED + wave * NL + l] = acc[l];
    __syncthreads();
    if (tid < NL) {
      float s = b_pc[tid];
#pragma unroll
      for (int w = 0; w < 4; ++w) s += sm[NFUSED + w * NL + tid];
      const float g = s > 0.f ? 1.f : 0.f;
      gate_ws[b * NL + tid] = g;
      gate_out[b * NL + tid] = g;
    }
  }
}

// =====================================================================
// K4: layer-reuse writers — 1280 blocks.
//   [0,256)    B: 8b x 8dc(512d) x 4lg(6l). CBT slice read once/block,
//              F-sum computed once (shared by the 6 layers).
//   [256,1280) A: encoded (lg<<8)|(b<<5)|(rc<<2)|dc: 4dc(1024d) x
//              8rc(8r) x 8b x 4lg(6l). CA slice read once per r,
//              reused across 6 layers.
//   B first: bigger blocks start early (tail balance). dc in low bits
//   keeps slice-sharing blocks on one XCD (round-robin heuristic).
// =====================================================================
__global__ __launch_bounds__(256) void k_out(
    const float* __restrict__ pFA, const float* __restrict__ pFB,
    const float* __restrict__ b_A, const float* __restrict__ b_B,
    const float* __restrict__ pLA, const float* __restrict__ pLB,
    const float* __restrict__ CA, const float* __restrict__ CBT,
    const float* __restrict__ gate,
    float* __restrict__ outA, float* __restrict__ outB) {
  __shared__ float sm[7 * 512];   // B: fsum[512] + sbase[6][512]
  const int bx = blockIdx.x;
  const int tid = threadIdx.x;

  if (bx < 256) {                       // ---- B writer (6 layers/block)
    const int dc = bx & 7;
    const int b  = (bx >> 3) & 7;
    const int lg = bx >> 6;             // 0..3
    const int dbase = dc * 512;
    float* fsum = sm;
    float* sbase = sm + 512;
    // F-sum + bias once (shared across the 6 layers)
    for (int dd = tid; dd < 512; dd += 256) {
      const int d = dbase + dd;
      float s = b_B[d];
#pragma unroll
      for (int kc = 0; kc < FKC; ++kc)
        s += pFB[(size_t)(kc * NB + b) * ND + d];
      fsum[dd] = s;
    }
    __syncthreads();
    for (int i = tid; i < 6 * 512; i += 256) {
      const int l = lg * 6 + (i >> 9);
      const int dd = i & 511;
      const int d = dbase + dd;
      sbase[i] = fsum[dd] + pLB[(size_t)l * ND + d] + pLB[(size_t)(NL + l) * ND + d];
    }
    __syncthreads();
    const int dd16 = tid >> 4;
    const int r4 = (tid & 15) * 4;
#pragma unroll 2
    for (int i = 0; i < 32; ++i) {
      const int dloc = i * 16 + dd16;
      const int d = dbase + dloc;
      const v4f c = *(const v4f*)(CBT + (size_t)d * NR + r4);
#pragma unroll
      for (int l = 0; l < 6; ++l) {
        const v4f v = c + sbase[l * 512 + dloc];
        const int bl = b * NL + lg * 6 + l;
        __builtin_nontemporal_store(v, (v4f*)(outB + ((size_t)bl * ND + d) * NR + r4));
      }
    }
  } else {                              // ---- A writer (6 layers/block)
    const int t = bx - 256;
    const int dc = t & 3;
    const int rc = (t >> 2) & 7;
    const int b  = (t >> 5) & 7;
    const int lg = t >> 8;              // 0..3
    const int dt = dc * 1024 + tid * 4;
    // F base once
    v4f Fb = *(const v4f*)(b_A + dt);
#pragma unroll
    for (int kc = 0; kc < FKC; ++kc)
      Fb += *(const v4f*)(pFA + (size_t)(kc * NB + b) * ND + dt);
    // per-layer adds + gates
    v4f pl[6];
    float g[6];
#pragma unroll
    for (int i = 0; i < 6; ++i) {
      const int l = lg * 6 + i;
      pl[i] = Fb + *(const v4f*)(pLA + (size_t)l * ND + dt)
                 + *(const v4f*)(pLA + (size_t)(NL + l) * ND + dt);
      g[i] = gate[b * NL + l];
    }
    const int r0 = rc * 8;
#pragma unroll 2
    for (int r = 0; r < 8; ++r) {
      const v4f c = *(const v4f*)(CA + (size_t)(r0 + r) * ND + dt);
#pragma unroll
      for (int i = 0; i < 6; ++i) {
        const v4f v = (pl[i] + c) * g[i];
        const int bl = b * NL + lg * 6 + i;
        __builtin_nontemporal_store(v, (v4f*)(outA + ((size_t)bl * NR + r0 + r) * ND + dt));
      }
    }
  }
}

extern "C" void kernel_launch(void* const* d_in, const int* in_sizes, int n_in,
                              void* d_out, int out_size, void* d_ws, size_t ws_size,
                              hipStream_t stream) {
  const float* A_small   = (const float*)d_in[0];
  const float* B_small   = (const float*)d_in[1];
  const float* prompt    = (const float*)d_in[2];
  const float* W_ct      = (const float*)d_in[3];
  const float* b_ct      = (const float*)d_in[4];
  const float* W_cp      = (const float*)d_in[5];
  const float* b_cp      = (const float*)d_in[6];
  const float* W_pc      = (const float*)d_in[7];
  const float* b_pc      = (const float*)d_in[8];
  const float* E_layer   = (const float*)d_in[9];
  const float* E_chunk   = (const float*)d_in[10];
  const float* W_A       = (const float*)d_in[11];
  const float* b_A       = (const float*)d_in[12];
  const float* W_B       = (const float*)d_in[13];
  const float* b_B       = (const float*)d_in[14];

  float* ws    = (float*)d_ws;
  float* fAcc  = ws + WS_FACC;
  float* gatew = ws + WS_GATE;
  float* pLA   = ws + WS_PLA;
  float* pLB   = ws + WS_PLB;
  float* CA    = ws + WS_CA;
  float* CBT   = ws + WS_CBT;
  float* pFA   = ws + WS_PFA;
  float* pFB   = ws + WS_PFB;

  float* outA = (float*)d_out;                       // [192,64,4096]
  float* outB = outA + (size_t)192 * NR * ND;        // [192,4096,64]
  float* outG = outB + (size_t)192 * ND * NR;        // [192]

  // zero the 4-replica fused accumulator
  hipMemsetAsync(fAcc, 0, (size_t)4 * NB * NFUSED * sizeof(float), stream);

  k_indep<<<736, 256, 0, stream>>>(A_small, B_small, W_ct, prompt, W_cp,
                                   E_layer, E_chunk, W_A, W_B,
                                   fAcc, pLA, pLB, CA, CBT);
  k_dep<<<392, 256, 0, stream>>>(fAcc, b_ct, b_cp, W_A, W_B,
                                 W_pc, b_pc, pFA, pFB, gatew, outG);
  k_out<<<1280, 256, 0, stream>>>(pFA, pFB, b_A, b_B, pLA, pLB, CA, CBT,
                                  gatew, outA, outB);
}

// Round 15
// 136.249 us; speedup vs baseline: 2.2610x; 1.0518x over previous
//
#include <hip/hip_runtime.h>

typedef float v4f __attribute__((ext_vector_type(4)));
typedef float v2f __attribute__((ext_vector_type(2)));

#define NB 8        // batch
#define NL 24       // layers
#define NR 64       // chunks
#define ND 4096     // DL
#define NFUSED 1536
#define NTF 1024
#define NPF 512
#define KP 4096     // DP

#define FKC 12      // F k-chunks of 128

// workspace float offsets (R7/R10 layout)
#define WS_FACC  0          // 4*8*1536 = 49152
#define WS_GATE  49152      // 192               -> 49344
#define WS_PLA   49344      // 2*24*4096=196608  -> 245952
#define WS_PLB   245952     // 196608            -> 442560
#define WS_CA    442560     // 262144            -> 704704
#define WS_CBT   704704     // 262144            -> 966848
#define WS_PFA   966848     // 12*8*4096=393216  -> 1360064
#define WS_PFB   1360064    // 393216            -> 1753280

// =====================================================================
// K1 — 416 blocks (float2 weight loads; atomic count unchanged vs R10):
//   [0,288)   tfeat partial: jc = bx&1 (512 j), kc = bx>>1 (144 of 128 k)
//   [288,320) pfeat partial: kc = bx-288 (32 of 128 k), full 512 j
//   [320,384) L_A / L_B   (16 d-chunks x 2 k-halves x 2 mats)
//   [384,416) C_A / C_BT  (16 d-chunks x 2 mats)
// =====================================================================
__global__ __launch_bounds__(256) void k_indep(
    const float* __restrict__ As, const float* __restrict__ Bs,
    const float* __restrict__ W_ct,
    const float* __restrict__ prompt, const float* __restrict__ W_cp,
    const float* __restrict__ E_layer, const float* __restrict__ E_chunk,
    const float* __restrict__ W_A, const float* __restrict__ W_B,
    float* __restrict__ fAcc,
    float* __restrict__ pLA, float* __restrict__ pLB,
    float* __restrict__ CA, float* __restrict__ CBT) {
  __shared__ float e[NR * 64];
  const int bx = blockIdx.x;
  const int tid = threadIdx.x;

  if (bx < 288) {                       // ---- tfeat partial (float2 W)
    const int j2 = (bx & 1) * 512 + tid * 2;
    const int kc = bx >> 1;             // [0,144)
    const int kbase = kc * 128;
    const float* xsrc = (kbase < 9216) ? (As + kbase) : (Bs + (kbase - 9216));
    {
      const int i0 = tid * 4;           // stage x[8][128]
      const int b = i0 >> 7, kk = i0 & 127;
      *(v4f*)&e[i0] = *(const v4f*)(xsrc + (size_t)b * 9216 + kk);
    }
    __syncthreads();
    v2f acc[NB] = {};
    for (int k4 = 0; k4 < 128; k4 += 4) {
      v4f xv[NB];
#pragma unroll
      for (int b = 0; b < NB; ++b) xv[b] = *(const v4f*)&e[b * 128 + k4];
#pragma unroll
      for (int u = 0; u < 4; ++u) {
        const v2f w = *(const v2f*)(W_ct + (size_t)(kbase + k4 + u) * NTF + j2);
#pragma unroll
        for (int b = 0; b < NB; ++b) acc[b] += xv[b][u] * w;
      }
    }
    const int rep = kc & 3;
#pragma unroll
    for (int b = 0; b < NB; ++b) {
      float* dst = fAcc + (size_t)(rep * NB + b) * NFUSED + j2;
      atomicAdd(dst + 0, acc[b][0]);
      atomicAdd(dst + 1, acc[b][1]);
    }
  } else if (bx < 320) {                // ---- pfeat partial (float2 W)
    const int kc = bx - 288;            // [0,32)
    const int j2 = tid * 2;
    const int kbase = kc * 128;
    {
      const int i0 = tid * 4;
      const int b = i0 >> 7, kk = i0 & 127;
      *(v4f*)&e[i0] = *(const v4f*)(prompt + (size_t)b * KP + kbase + kk);
    }
    __syncthreads();
    v2f acc[NB] = {};
    for (int k4 = 0; k4 < 128; k4 += 4) {
      v4f xv[NB];
#pragma unroll
      for (int b = 0; b < NB; ++b) xv[b] = *(const v4f*)&e[b * 128 + k4];
#pragma unroll
      for (int u = 0; u < 4; ++u) {
        const v2f w = *(const v2f*)(W_cp + (size_t)(kbase + k4 + u) * NPF + j2);
#pragma unroll
        for (int b = 0; b < NB; ++b) acc[b] += xv[b][u] * w;
      }
    }
    const int rep = kc & 3;
#pragma unroll
    for (int b = 0; b < NB; ++b) {
      float* dst = fAcc + (size_t)(rep * NB + b) * NFUSED + NTF + j2;
      atomicAdd(dst + 0, acc[b][0]);
      atomicAdd(dst + 1, acc[b][1]);
    }
  } else if (bx < 384) {                // ---- L_A / L_B (split-K 2 halves)
    const int t = bx - 320;
    const bool isA = t < 32;
    const int tt = isA ? t : t - 32;
    const int dc = tt & 15;
    const int kh = tt >> 4;             // 0 or 1
    const float* W = (isA ? W_A : W_B) + (size_t)(NFUSED + kh * 128) * ND;
    float* pL = (isA ? pLA : pLB) + (size_t)kh * NL * ND;
    const int d = dc * 256 + tid;
    float acc[NL] = {};
    for (int kk = 0; kk < 128; ++kk) {
      const float w = W[(size_t)kk * ND + d];
      const float* el = E_layer + kh * 128 + kk;
#pragma unroll
      for (int l = 0; l < NL; ++l) acc[l] = fmaf(el[l * 256], w, acc[l]);
    }
#pragma unroll
    for (int l = 0; l < NL; ++l) pL[(size_t)l * ND + d] = acc[l];
  } else {                              // ---- C_A / C_BT
    const int t = bx - 384;
    const bool isA = t < 16;
    const int tt = isA ? t : t - 16;
    const float* W = (isA ? W_A : W_B) + (size_t)(NFUSED + 256) * ND;
    for (int i = tid; i < NR * 64; i += 256) e[i] = E_chunk[i];
    __syncthreads();
    const int d = tt * 256 + tid;
    float w[64];
#pragma unroll
    for (int k = 0; k < 64; ++k) w[k] = W[(size_t)k * ND + d];
    for (int r = 0; r < NR; ++r) {
      float s = 0.f;
#pragma unroll
      for (int k = 0; k < 64; ++k) s = fmaf(e[r * 64 + k], w[k], s);
      if (isA) CA[(size_t)r * ND + d] = s;
      else     CBT[(size_t)d * NR + r] = s;
    }
  }
}

// =====================================================================
// K3 — 200 blocks (F partials use float2 W loads):
//   [0,96)    F_A: dc = t&7 (512 d), kc = t>>3 (12)
//   [96,192)  F_B
//   [192,200) gate, one batch per block
// =====================================================================
__global__ __launch_bounds__(256) void k_dep(
    const float* __restrict__ fAcc,
    const float* __restrict__ b_ct, const float* __restrict__ b_cp,
    const float* __restrict__ W_A, const float* __restrict__ W_B,
    const float* __restrict__ W_pc, const float* __restrict__ b_pc,
    float* __restrict__ pFA, float* __restrict__ pFB,
    float* __restrict__ gate_ws, float* __restrict__ gate_out) {
  __shared__ float sm[1664];
  const int bx = blockIdx.x;
  const int tid = threadIdx.x;

  if (bx < 192) {                       // ---- F partial (float2 W)
    const bool isA = bx < 96;
    const int t = isA ? bx : bx - 96;
    const float* W = isA ? W_A : W_B;
    float* part = isA ? pFA : pFB;
    const int dc = t & 7;
    const int kc = t >> 3;              // [0,12)
    const int kbase = kc * 128;

    // stage fused slice [8][128]: replica-sum + bias + relu
    for (int i = tid; i < 1024; i += 256) {
      const int b = i >> 7, kk = i & 127;
      const int k = kbase + kk;
      float v = (k < NTF) ? b_ct[k] : b_cp[k - NTF];
#pragma unroll
      for (int rep = 0; rep < 4; ++rep)
        v += fAcc[(size_t)(rep * NB + b) * NFUSED + k];
      sm[i] = fmaxf(v, 0.f);
    }
    __syncthreads();

    const int d2 = dc * 512 + tid * 2;
    v2f acc[NB] = {};
    for (int kk = 0; kk < 128; ++kk) {
      const v2f w = *(const v2f*)(W + (size_t)(kbase + kk) * ND + d2);
#pragma unroll
      for (int b = 0; b < NB; ++b) acc[b] += sm[b * 128 + kk] * w;
    }
#pragma unroll
    for (int b = 0; b < NB; ++b)
      *(v2f*)(part + (size_t)(kc * NB + b) * ND + d2) = acc[b];
  } else {                              // ---- gate for batch b
    const int b = bx - 192;
    for (int j = tid; j < NFUSED; j += 256) {
      float v = (j < NTF) ? b_ct[j] : b_cp[j - NTF];
#pragma unroll
      for (int rep = 0; rep < 4; ++rep)
        v += fAcc[(size_t)(rep * NB + b) * NFUSED + j];
      sm[j] = fmaxf(v, 0.f);
    }
    __syncthreads();
    float acc[NL] = {};
    for (int j = tid; j < NFUSED; j += 256) {
      const float f = sm[j];
#pragma unroll
      for (int l = 0; l < NL; ++l) acc[l] = fmaf(f, W_pc[j * NL + l], acc[l]);
    }
#pragma unroll
    for (int off = 32; off > 0; off >>= 1)
#pragma unroll
      for (int l = 0; l < NL; ++l) acc[l] += __shfl_down(acc[l], off);
    const int wave = tid >> 6, lane = tid & 63;
    if (lane == 0)
#pragma unroll
      for (int l = 0; l < NL; ++l) sm[NFUSED + wave * NL + l] = acc[l];
    __syncthreads();
    if (tid < NL) {
      float s = b_pc[tid];
#pragma unroll
      for (int w = 0; w < 4; ++w) s += sm[NFUSED + w * NL + tid];
      const float g = s > 0.f ? 1.f : 0.f;
      gate_ws[b * NL + tid] = g;
      gate_out[b * NL + tid] = g;
    }
  }
}

// =====================================================================
// K4: writers — 3072 blocks (R10 verbatim, NT output stores)
// =====================================================================
__global__ __launch_bounds__(256) void k_out(
    const float* __restrict__ pFA, const float* __restrict__ pFB,
    const float* __restrict__ b_A, const float* __restrict__ b_B,
    const float* __restrict__ pLA, const float* __restrict__ pLB,
    const float* __restrict__ CA, const float* __restrict__ CBT,
    const float* __restrict__ gate,
    float* __restrict__ outA, float* __restrict__ outB) {
  __shared__ float sbase[512];
  const int bx = blockIdx.x;
  const int tid = threadIdx.x;
  if (bx < 1536) {                      // ---- A writer
    const int bl = bx >> 3;
    const int rest = bx & 7;
    const int b = bl / NL, l = bl % NL;
    const int d = (rest >> 1) * 1024 + tid * 4;
    const int r0 = (rest & 1) * 32;
    const float g = gate[bl];
    v4f base = *(const v4f*)(b_A + d);
#pragma unroll
    for (int kc = 0; kc < FKC; ++kc)
      base += *(const v4f*)(pFA + (size_t)(kc * NB + b) * ND + d);
    base += *(const v4f*)(pLA + (size_t)l * ND + d);
    base += *(const v4f*)(pLA + (size_t)(NL + l) * ND + d);
    float* outp = outA + ((size_t)bl * NR + r0) * ND + d;
#pragma unroll 4
    for (int r = 0; r < 32; ++r) {
      const v4f c = *(const v4f*)(CA + (size_t)(r0 + r) * ND + d);
      const v4f v = (base + c) * g;
      __builtin_nontemporal_store(v, (v4f*)outp);
      outp += ND;
    }
  } else {                              // ---- B writer
    const int t = bx - 1536;
    const int bl = t >> 3;
    const int b = bl / NL, l = bl % NL;
    const int dbase = (t & 7) * 512;
    for (int dd = tid; dd < 512; dd += 256) {
      const int d = dbase + dd;
      float s = b_B[d] + pLB[(size_t)l * ND + d] + pLB[(size_t)(NL + l) * ND + d];
#pragma unroll
      for (int kc = 0; kc < FKC; ++kc)
        s += pFB[(size_t)(kc * NB + b) * ND + d];
      sbase[dd] = s;
    }
    __syncthreads();
    const int dd16 = tid >> 4;
    const int r4 = (tid & 15) * 4;
#pragma unroll 4
    for (int i = 0; i < 32; ++i) {
      const int dloc = i * 16 + dd16;
      const int d = dbase + dloc;
      const v4f c = *(const v4f*)(CBT + (size_t)d * NR + r4);
      const v4f v = c + sbase[dloc];
      __builtin_nontemporal_store(v, (v4f*)(outB + ((size_t)bl * ND + d) * NR + r4));
    }
  }
}

extern "C" void kernel_launch(void* const* d_in, const int* in_sizes, int n_in,
                              void* d_out, int out_size, void* d_ws, size_t ws_size,
                              hipStream_t stream) {
  const float* A_small   = (const float*)d_in[0];
  const float* B_small   = (const float*)d_in[1];
  const float* prompt    = (const float*)d_in[2];
  const float* W_ct      = (const float*)d_in[3];
  const float* b_ct      = (const float*)d_in[4];
  const float* W_cp      = (const float*)d_in[5];
  const float* b_cp      = (const float*)d_in[6];
  const float* W_pc      = (const float*)d_in[7];
  const float* b_pc      = (const float*)d_in[8];
  const float* E_layer   = (const float*)d_in[9];
  const float* E_chunk   = (const float*)d_in[10];
  const float* W_A       = (const float*)d_in[11];
  const float* b_A       = (const float*)d_in[12];
  const float* W_B       = (const float*)d_in[13];
  const float* b_B       = (const float*)d_in[14];

  float* ws    = (float*)d_ws;
  float* fAcc  = ws + WS_FACC;
  float* gatew = ws + WS_GATE;
  float* pLA   = ws + WS_PLA;
  float* pLB   = ws + WS_PLB;
  float* CA    = ws + WS_CA;
  float* CBT   = ws + WS_CBT;
  float* pFA   = ws + WS_PFA;
  float* pFB   = ws + WS_PFB;

  float* outA = (float*)d_out;                       // [192,64,4096]
  float* outB = outA + (size_t)192 * NR * ND;        // [192,4096,64]
  float* outG = outB + (size_t)192 * ND * NR;        // [192]

  // zero the 4-replica fused accumulator
  hipMemsetAsync(fAcc, 0, (size_t)4 * NB * NFUSED * sizeof(float), stream);

  k_indep<<<416, 256, 0, stream>>>(A_small, B_small, W_ct, prompt, W_cp,
                                   E_layer, E_chunk, W_A, W_B,
                                   fAcc, pLA, pLB, CA, CBT);
  k_dep<<<200, 256, 0, stream>>>(fAcc, b_ct, b_cp, W_A, W_B,
                                 W_pc, b_pc, pFA, pFB, gatew, outG);
  k_out<<<3072, 256, 0, stream>>>(pFA, pFB, b_A, b_B, pLA, pLB, CA, CBT,
                                  gatew, outA, outB);
}